// Round 10
// baseline (824.931 us; speedup 1.0000x reference)
//
#include <hip/hip_runtime.h>
#include <hip/hip_fp16.h>

// ScaledDotProductAttention: context = softmax(QK^T/sqrt(d) - 100*mask) @ V
// B=32 Tq=2048 Tk=1024 d=128 dv=256, fp32 in/out.
// R10: (a) cal_w = 8 full passes of textbook contiguous stores over the score
// region (2.1 GB) -- sized to be the SLOWEST dispatch so its hbm_gbps row is
// guaranteed visible in the profile: the definitive write-path ceiling
// measurement. (b) all nontemporal stores reverted (R9: 2.2x write
// amplification). (c) k2 PV pipeline deepened 2->4 (16 outstanding V loads)
// to test the latency/MLP hypothesis independently.

namespace {

constexpr int kB = 32, kTq = 2048, kTk = 1024, kD = 128, kDv = 256;
constexpr float kScale = 0.08838834764831845f;  // 1/sqrt(128)

typedef _Float16 half8 __attribute__((ext_vector_type(8)));
typedef _Float16 half4 __attribute__((ext_vector_type(4)));
typedef float    f32x4 __attribute__((ext_vector_type(4)));

// workspace layout (~24.3 MiB)
constexpr size_t kWsK   = 0;          // K16 [32][1024][128] f16 = 8 MiB
constexpr size_t kWsV   = 8388608;    // VT  [32][256][1024] f16 = 16 MiB
constexpr size_t kWsInv = 25165824;   // inv rowsum [32*2048] f32 = 256 KiB

__device__ __forceinline__ int pswz(int row, int cb) {  // row<32, cb<2048 bytes
  return row * 2048 + (cb ^ ((row & 7) << 4));
}

struct Frag4 { half8 a, b, c, d; };

// ---- calibration: 8 full passes of contiguous f32x4 stores over the score
// region (268 MB x 8 = 2.1 GB). Overwritten by k1/k2 afterwards. ----
__global__ __launch_bounds__(256)
void cal_w(float* __restrict__ dst) {
  const size_t stride = (size_t)2048 * 256 * 4;   // floats per grid sweep
  const size_t base = ((size_t)blockIdx.x * 256 + threadIdx.x) * 4;
  const f32x4 z = {0.f, 0.f, 0.f, 0.f};
  for (int p = 0; p < 8; ++p) {
    size_t i = base;
#pragma unroll 8
    for (int it = 0; it < 32; ++it) {     // 32 sweeps x 8 MB = 268 MB
      *(f32x4*)(dst + i) = z;
      i += stride;
    }
  }
}

// ---- pre-kernel 1: K f32 -> f16 ----
__global__ __launch_bounds__(256)
void cvt_k(const float* __restrict__ in, _Float16* __restrict__ out) {
  int i = (blockIdx.x * 256 + threadIdx.x) * 8;
  f32x4 a = *(const f32x4*)(in + i);
  f32x4 b = *(const f32x4*)(in + i + 4);
  half8 h;
  h[0] = a[0]; h[1] = a[1]; h[2] = a[2]; h[3] = a[3];
  h[4] = b[0]; h[5] = b[1]; h[6] = b[2]; h[7] = b[3];
  *(half8*)(out + i) = h;
}

// ---- pre-kernel 2: V [k][dv] f32 -> V^T [dv][k] f16 ----
__global__ __launch_bounds__(256)
void trans_v(const float* __restrict__ v, _Float16* __restrict__ vt) {
  __shared__ _Float16 t[64 * 66];
  const int b   = blockIdx.x >> 6;
  const int idx = blockIdx.x & 63;
  const int k0  = (idx & 15) * 64;
  const int d0  = (idx >> 4) * 64;
  const int r = threadIdx.x >> 6, c = threadIdx.x & 63;
#pragma unroll 4
  for (int it = 0; it < 16; ++it) {
    float x = v[((size_t)b * kTk + k0 + it * 4 + r) * kDv + d0 + c];
    t[c * 66 + it * 4 + r] = (_Float16)x;
  }
  __syncthreads();
  const int dr = threadIdx.x >> 4, kc = (threadIdx.x & 15) * 4;
#pragma unroll
  for (int it = 0; it < 4; ++it) {
    int drow = it * 16 + dr;
    half4 h;
#pragma unroll
    for (int j = 0; j < 4; ++j) h[j] = t[drow * 66 + kc + j];
    *(half4*)(vt + ((size_t)b * kDv + d0 + drow) * kTk + k0 + kc) = h;
  }
}

// ---- K1: QK^T -> logits(LDS) -> mask sweep + exp -> e + 1/rowsum (R8) ----
__global__ __launch_bounds__(512, 4)
void k1_logits(const float* __restrict__ qg, const _Float16* __restrict__ K16,
               const float* __restrict__ mg, float* __restrict__ out,
               float* __restrict__ inv_ws) {
  __shared__ __align__(16) unsigned char s_[65536];

  const int tid  = threadIdx.x;
  const int lane = tid & 63;
  const int wid  = tid >> 6;     // 0..7
  const int l15  = lane & 15;
  const int lg   = lane >> 4;    // 0..3

  const int bi    = blockIdx.x;               // 0..2047
  const int batch = (bi & 7) * 4 + (bi >> 9); // XCD-grouped
  const int q0    = ((bi >> 3) & 63) * 32;

  const float* Q = qg + ((size_t)batch * kTq + q0) * kD;
  const _Float16* Kb = K16 + (size_t)batch * kTk * kD;
  const float* M = mg + ((size_t)batch * kTq + q0) * kTk;
  char* Ebase = (char*)(out + (size_t)kB * kTq * kDv) +
                ((size_t)batch * kTq + q0) * 4096;

  // ===== Phase A: QK^T -> logits*scale f16 in LDS =====
  const int wr = wid >> 2;   // 0..1
  const int wc = wid & 3;    // 0..3
  half8 qf[4];
  {
    const float* qrow = Q + (size_t)(wr * 16 + l15) * kD + lg * 8;
#pragma unroll
    for (int c = 0; c < 4; ++c) {
      f32x4 a = *(const f32x4*)(qrow + c * 32);
      f32x4 b = *(const f32x4*)(qrow + c * 32 + 4);
      half8 h;
      h[0] = a[0]; h[1] = a[1]; h[2] = a[2]; h[3] = a[3];
      h[4] = b[0]; h[5] = b[1]; h[6] = b[2]; h[7] = b[3];
      qf[c] = h;
    }
  }
  auto ldK = [&](int s, half8* f) {
    const _Float16* p = Kb + (size_t)(s * 64 + wc * 16 + l15) * kD + lg * 8;
    f[0] = *(const half8*)(p);
    f[1] = *(const half8*)(p + 32);
    f[2] = *(const half8*)(p + 64);
    f[3] = *(const half8*)(p + 96);
  };
  auto qk = [&](const half8* f) -> f32x4 {
    f32x4 acc = {0.f, 0.f, 0.f, 0.f};
    acc = __builtin_amdgcn_mfma_f32_16x16x32_f16(qf[0], f[0], acc, 0, 0, 0);
    acc = __builtin_amdgcn_mfma_f32_16x16x32_f16(qf[1], f[1], acc, 0, 0, 0);
    acc = __builtin_amdgcn_mfma_f32_16x16x32_f16(qf[2], f[2], acc, 0, 0, 0);
    acc = __builtin_amdgcn_mfma_f32_16x16x32_f16(qf[3], f[3], acc, 0, 0, 0);
    return acc;
  };
  auto stP = [&](f32x4 acc, int s) {
    int colb = (s * 64 + wc * 16 + l15) * 2;
#pragma unroll
    for (int j = 0; j < 4; ++j)
      *(_Float16*)(s_ + pswz(wr * 16 + lg * 4 + j, colb)) =
          (_Float16)(acc[j] * kScale);
  };
  half8 fA[4], fB[4];
  ldK(0, fA); ldK(1, fB);
  for (int s = 0; s < 16; s += 2) {
    __builtin_amdgcn_s_setprio(1);
    f32x4 a0 = qk(fA);
    __builtin_amdgcn_s_setprio(0);
    if (s + 2 < 16) ldK(s + 2, fA);
    stP(a0, s);
    __builtin_amdgcn_s_setprio(1);
    f32x4 a1 = qk(fB);
    __builtin_amdgcn_s_setprio(0);
    if (s + 3 < 16) ldK(s + 3, fB);
    stP(a1, s + 1);
  }
  __syncthreads();

  // ===== Phase B: per-wave contiguous row sweeps (R8 form, no nt) =====
  const int r0 = wid * 4;
  f32x4 cA = *(const f32x4*)(M + (size_t)r0 * kTk + lane * 8);
  f32x4 cB = *(const f32x4*)(M + (size_t)r0 * kTk + lane * 8 + 4);
  f32x4 nA, nB;
  float rs = 0.f;
#pragma unroll
  for (int it = 0; it < 8; ++it) {
    const int r = r0 + (it >> 1), h = it & 1;
    if (it < 7) {
      const int rn = r0 + ((it + 1) >> 1), hn = (it + 1) & 1;
      nA = *(const f32x4*)(M + (size_t)rn * kTk + hn * 512 + lane * 8);
      nB = *(const f32x4*)(M + (size_t)rn * kTk + hn * 512 + lane * 8 + 4);
    }
    half8 sv = *(const half8*)(s_ + pswz(r, h * 1024 + lane * 16));
    float e0 = __expf((float)sv[0] - 100.f * cA[0]);
    float e1 = __expf((float)sv[1] - 100.f * cA[1]);
    float e2 = __expf((float)sv[2] - 100.f * cA[2]);
    float e3 = __expf((float)sv[3] - 100.f * cA[3]);
    float e4 = __expf((float)sv[4] - 100.f * cB[0]);
    float e5 = __expf((float)sv[5] - 100.f * cB[1]);
    float e6 = __expf((float)sv[6] - 100.f * cB[2]);
    float e7 = __expf((float)sv[7] - 100.f * cB[3]);
    rs += ((e0 + e1) + (e2 + e3)) + ((e4 + e5) + (e6 + e7));
    half8 ev;
    ev[0] = e0; ev[1] = e1; ev[2] = e2; ev[3] = e3;
    ev[4] = e4; ev[5] = e5; ev[6] = e6; ev[7] = e7;
    *(half8*)(Ebase + (size_t)r * 4096 + h * 1024 + lane * 16) = ev;
    if (h == 1) {
      rs += __shfl_xor(rs, 1);  rs += __shfl_xor(rs, 2);
      rs += __shfl_xor(rs, 4);  rs += __shfl_xor(rs, 8);
      rs += __shfl_xor(rs, 16); rs += __shfl_xor(rs, 32);
      if (lane == 0) inv_ws[(size_t)batch * kTq + q0 + r] = 1.0f / rs;
      rs = 0.f;
    }
    cA = nA; cB = nB;
  }
}

// ---- K2: e sweep -> score + LDS P; PV MFMA (4-deep); ctx ----
__global__ __launch_bounds__(512, 4)
void k2_pv(const _Float16* __restrict__ VT, const float* __restrict__ inv_ws,
           float* __restrict__ out) {
  __shared__ __align__(16) unsigned char s_[65536];

  const int tid  = threadIdx.x;
  const int lane = tid & 63;
  const int wid  = tid >> 6;     // 0..7
  const int l15  = lane & 15;
  const int lg   = lane >> 4;    // 0..3

  const int bi    = blockIdx.x;
  const int batch = (bi & 7) * 4 + (bi >> 9);
  const int q0    = ((bi >> 3) & 63) * 32;

  float* CTX = out + ((size_t)batch * kTq + q0) * kDv;
  float* SCR = out + (size_t)kB * kTq * kDv + ((size_t)batch * kTq + q0) * kTk;
  const char* Ebase = (const char*)SCR;
  const _Float16* Vb = VT + (size_t)batch * kDv * kTk;
  const float* INV = inv_ws + (size_t)batch * kTq + q0;

  const int r0 = wid * 4;
  f32x4 iv = *(const f32x4*)(INV + r0);

  // ===== Phase A: e sweep -> score (R8 form: h=1 then h=0, no nt) =====
  half8 evc, evn;
  evc = *(const half8*)(Ebase + (size_t)r0 * 4096 + 1024 + lane * 16);
#pragma unroll
  for (int it = 0; it < 8; ++it) {
    const int r = r0 + (it >> 1), h = 1 - (it & 1);
    if (it < 7) {
      const int rn = r0 + ((it + 1) >> 1), hn = 1 - ((it + 1) & 1);
      evn = *(const half8*)(Ebase + (size_t)rn * 4096 + hn * 1024 + lane * 16);
    }
    const float inv = iv[it >> 1];
    f32x4 oA, oB;
    oA[0] = (float)evc[0] * inv; oA[1] = (float)evc[1] * inv;
    oA[2] = (float)evc[2] * inv; oA[3] = (float)evc[3] * inv;
    oB[0] = (float)evc[4] * inv; oB[1] = (float)evc[5] * inv;
    oB[2] = (float)evc[6] * inv; oB[3] = (float)evc[7] * inv;
    *(f32x4*)(SCR + (size_t)r * kTk + h * 512 + lane * 8)     = oA;
    *(f32x4*)(SCR + (size_t)r * kTk + h * 512 + lane * 8 + 4) = oB;
    *(half8*)(s_ + pswz(r, h * 1024 + lane * 16)) = evc;
    evc = evn;
  }
  __syncthreads();

  // ===== Phase B: PV = P(LDS) x VT(L2), 4-deep (16 outstanding V loads) ====
  const int wr = wid >> 2;
  const int wc = wid & 3;
  auto ldP = [&](int kc) -> half8 {
    return *(const half8*)(s_ + pswz(wr * 16 + l15, kc * 64 + lg * 16));
  };
  auto ldV = [&](int kc) -> Frag4 {
    const _Float16* p = Vb + (size_t)(wc * 64 + l15) * kTk + kc * 32 + lg * 8;
    Frag4 f;
    f.a = *(const half8*)(p);
    f.b = *(const half8*)(p + (size_t)16 * kTk);
    f.c = *(const half8*)(p + (size_t)32 * kTk);
    f.d = *(const half8*)(p + (size_t)48 * kTk);
    return f;
  };
  f32x4 c0 = {0,0,0,0}, c1 = {0,0,0,0}, c2 = {0,0,0,0}, c3 = {0,0,0,0};
  auto mm = [&](const half8& p, const Frag4& v) {
    __builtin_amdgcn_s_setprio(1);
    c0 = __builtin_amdgcn_mfma_f32_16x16x32_f16(p, v.a, c0, 0, 0, 0);
    c1 = __builtin_amdgcn_mfma_f32_16x16x32_f16(p, v.b, c1, 0, 0, 0);
    c2 = __builtin_amdgcn_mfma_f32_16x16x32_f16(p, v.c, c2, 0, 0, 0);
    c3 = __builtin_amdgcn_mfma_f32_16x16x32_f16(p, v.d, c3, 0, 0, 0);
    __builtin_amdgcn_s_setprio(0);
  };
  half8 p0 = ldP(0), p1 = ldP(1), p2 = ldP(2), p3 = ldP(3);
  Frag4 v0 = ldV(0), v1 = ldV(1), v2 = ldV(2), v3 = ldV(3);
  for (int kc = 0; kc < 32; kc += 4) {
    mm(p0, v0); if (kc + 4 < 32) { p0 = ldP(kc + 4); v0 = ldV(kc + 4); }
    mm(p1, v1); if (kc + 5 < 32) { p1 = ldP(kc + 5); v1 = ldV(kc + 5); }
    mm(p2, v2); if (kc + 6 < 32) { p2 = ldP(kc + 6); v2 = ldV(kc + 6); }
    mm(p3, v3); if (kc + 7 < 32) { p3 = ldP(kc + 7); v3 = ldV(kc + 7); }
  }
  __syncthreads();           // P region free -> reuse as f32 ctx stage

  // ===== ctx: stage to LDS, then contiguous sweeps =====
  float* sf = (float*)s_;    // [32][256] f32
#pragma unroll
  for (int j = 0; j < 4; ++j) {
    const int row = wr * 16 + lg * 4 + j;
    sf[row * 256 + wc * 64 + l15]      = c0[j];
    sf[row * 256 + wc * 64 + 16 + l15] = c1[j];
    sf[row * 256 + wc * 64 + 32 + l15] = c2[j];
    sf[row * 256 + wc * 64 + 48 + l15] = c3[j];
  }
  __syncthreads();
#pragma unroll
  for (int rr = 0; rr < 4; ++rr) {
    const int r = r0 + rr;
    f32x4 v = *(const f32x4*)(sf + r * 256 + lane * 4);
    const float inv = iv[rr];
    v[0] *= inv; v[1] *= inv; v[2] *= inv; v[3] *= inv;
    *(f32x4*)(CTX + (size_t)r * kDv + lane * 4) = v;
  }
}

}  // namespace

extern "C" void kernel_launch(void* const* d_in, const int* in_sizes, int n_in,
                              void* d_out, int out_size, void* d_ws, size_t ws_size,
                              hipStream_t stream) {
  const float* q = (const float*)d_in[0];
  const float* k = (const float*)d_in[1];
  const float* v = (const float*)d_in[2];
  const float* m = (const float*)d_in[3];
  float* out = (float*)d_out;
  (void)in_sizes; (void)n_in; (void)out_size; (void)ws_size;

  _Float16* k16 = (_Float16*)((char*)d_ws + kWsK);
  _Float16* vt  = (_Float16*)((char*)d_ws + kWsV);
  float*    inv = (float*)((char*)d_ws + kWsInv);

  float* scr = out + (size_t)kB * kTq * kDv;   // score region base

  // calibration: 2.1 GB contiguous write to the exact buffer k2 writes.
  // Overwritten by k1/k2 below -> output unchanged.
  hipLaunchKernelGGL(cal_w, dim3(2048), dim3(256), 0, stream, scr);

  hipLaunchKernelGGL(cvt_k, dim3(kB * kTk * kD / (256 * 8)), dim3(256), 0, stream,
                     k, k16);
  hipLaunchKernelGGL(trans_v, dim3(kB * 64), dim3(256), 0, stream, v, vt);
  hipLaunchKernelGGL(k1_logits, dim3(2048), dim3(512), 0, stream,
                     q, k16, m, out, inv);
  hipLaunchKernelGGL(k2_pv, dim3(2048), dim3(512), 0, stream, vt, inv, out);
}

// Round 11
// 654.700 us; speedup vs baseline: 1.2600x; 1.2600x over previous
//
#include <hip/hip_runtime.h>
#include <hip/hip_fp16.h>

// ScaledDotProductAttention: context = softmax(QK^T/sqrt(d) - 100*mask) @ V
// B=32 Tq=2048 Tk=1024 d=128 dv=256, fp32 in/out.
// R11: full phase separation (attribution + cal_w-shaped streamers).
//   cvt_k, trans_v: staging (proven).
//   k1a: QK^T -> logits*scale f16 -> upper 2KB of each 4KB score slot.
//   k1b: PURE STREAM: logits+mask -> exp -> e (lower 2KB) + 1/rowsum (ws).
//   k2b: PV MFMA (e frags + VT) + ctx. Runs before e is clobbered.
//   k2a: PURE STREAM: e -> normalized score (full 4KB/row, race-free
//        whole-row-per-wave, upper-chunk-first ordering).
// cal_w (R10) proved 6.85 TB/s on this exact buffer; streamers mimic it.

namespace {

constexpr int kB = 32, kTq = 2048, kTk = 1024, kD = 128, kDv = 256;
constexpr float kScale = 0.08838834764831845f;  // 1/sqrt(128)

typedef _Float16 half8 __attribute__((ext_vector_type(8)));
typedef _Float16 half4 __attribute__((ext_vector_type(4)));
typedef float    f32x4 __attribute__((ext_vector_type(4)));

constexpr size_t kWsK   = 0;          // K16 [32][1024][128] f16 = 8 MiB
constexpr size_t kWsV   = 8388608;    // VT  [32][256][1024] f16 = 16 MiB
constexpr size_t kWsInv = 25165824;   // inv rowsum [65536] f32 = 256 KiB

__device__ __forceinline__ int pswz(int row, int cb) {  // row<32, cb<2048 bytes
  return row * 2048 + (cb ^ ((row & 7) << 4));
}

struct Frag4 { half8 a, b, c, d; };

// ---- pre-kernel 1: K f32 -> f16 ----
__global__ __launch_bounds__(256)
void cvt_k(const float* __restrict__ in, _Float16* __restrict__ out) {
  int i = (blockIdx.x * 256 + threadIdx.x) * 8;
  f32x4 a = *(const f32x4*)(in + i);
  f32x4 b = *(const f32x4*)(in + i + 4);
  half8 h;
  h[0] = a[0]; h[1] = a[1]; h[2] = a[2]; h[3] = a[3];
  h[4] = b[0]; h[5] = b[1]; h[6] = b[2]; h[7] = b[3];
  *(half8*)(out + i) = h;
}

// ---- pre-kernel 2: V [k][dv] f32 -> V^T [dv][k] f16 ----
__global__ __launch_bounds__(256)
void trans_v(const float* __restrict__ v, _Float16* __restrict__ vt) {
  __shared__ _Float16 t[64 * 66];
  const int b   = blockIdx.x >> 6;
  const int idx = blockIdx.x & 63;
  const int k0  = (idx & 15) * 64;
  const int d0  = (idx >> 4) * 64;
  const int r = threadIdx.x >> 6, c = threadIdx.x & 63;
#pragma unroll 4
  for (int it = 0; it < 16; ++it) {
    float x = v[((size_t)b * kTk + k0 + it * 4 + r) * kDv + d0 + c];
    t[c * 66 + it * 4 + r] = (_Float16)x;
  }
  __syncthreads();
  const int dr = threadIdx.x >> 4, kc = (threadIdx.x & 15) * 4;
#pragma unroll
  for (int it = 0; it < 4; ++it) {
    int drow = it * 16 + dr;
    half4 h;
#pragma unroll
    for (int j = 0; j < 4; ++j) h[j] = t[drow * 66 + kc + j];
    *(half4*)(vt + ((size_t)b * kDv + d0 + drow) * kTk + k0 + kc) = h;
  }
}

// ---- k1a: QK^T -> logits*scale f16 -> upper 2KB of score slots ----
__global__ __launch_bounds__(512, 4)
void k1a_qkt(const float* __restrict__ qg, const _Float16* __restrict__ K16,
             float* __restrict__ out) {
  __shared__ __align__(16) unsigned char s_[65536];

  const int tid  = threadIdx.x;
  const int lane = tid & 63;
  const int wid  = tid >> 6;     // 0..7
  const int l15  = lane & 15;
  const int lg   = lane >> 4;    // 0..3

  const int bi    = blockIdx.x;               // 0..2047
  const int batch = (bi & 7) * 4 + (bi >> 9); // XCD-grouped
  const int q0    = ((bi >> 3) & 63) * 32;

  const float* Q = qg + ((size_t)batch * kTq + q0) * kD;
  const _Float16* Kb = K16 + (size_t)batch * kTk * kD;
  char* Sl = (char*)(out + (size_t)kB * kTq * kDv) +
             ((size_t)batch * kTq + q0) * 4096;

  const int wr = wid >> 2;   // 0..1
  const int wc = wid & 3;    // 0..3
  half8 qf[4];
  {
    const float* qrow = Q + (size_t)(wr * 16 + l15) * kD + lg * 8;
#pragma unroll
    for (int c = 0; c < 4; ++c) {
      f32x4 a = *(const f32x4*)(qrow + c * 32);
      f32x4 b = *(const f32x4*)(qrow + c * 32 + 4);
      half8 h;
      h[0] = a[0]; h[1] = a[1]; h[2] = a[2]; h[3] = a[3];
      h[4] = b[0]; h[5] = b[1]; h[6] = b[2]; h[7] = b[3];
      qf[c] = h;
    }
  }
  auto ldK = [&](int s, half8* f) {
    const _Float16* p = Kb + (size_t)(s * 64 + wc * 16 + l15) * kD + lg * 8;
    f[0] = *(const half8*)(p);
    f[1] = *(const half8*)(p + 32);
    f[2] = *(const half8*)(p + 64);
    f[3] = *(const half8*)(p + 96);
  };
  auto qk = [&](const half8* f) -> f32x4 {
    f32x4 acc = {0.f, 0.f, 0.f, 0.f};
    acc = __builtin_amdgcn_mfma_f32_16x16x32_f16(qf[0], f[0], acc, 0, 0, 0);
    acc = __builtin_amdgcn_mfma_f32_16x16x32_f16(qf[1], f[1], acc, 0, 0, 0);
    acc = __builtin_amdgcn_mfma_f32_16x16x32_f16(qf[2], f[2], acc, 0, 0, 0);
    acc = __builtin_amdgcn_mfma_f32_16x16x32_f16(qf[3], f[3], acc, 0, 0, 0);
    return acc;
  };
  auto stP = [&](f32x4 acc, int s) {
    int colb = (s * 64 + wc * 16 + l15) * 2;
#pragma unroll
    for (int j = 0; j < 4; ++j)
      *(_Float16*)(s_ + pswz(wr * 16 + lg * 4 + j, colb)) =
          (_Float16)(acc[j] * kScale);
  };
  half8 fA[4], fB[4];
  ldK(0, fA); ldK(1, fB);
  for (int s = 0; s < 16; s += 2) {
    __builtin_amdgcn_s_setprio(1);
    f32x4 a0 = qk(fA);
    __builtin_amdgcn_s_setprio(0);
    if (s + 2 < 16) ldK(s + 2, fA);
    stP(a0, s);
    __builtin_amdgcn_s_setprio(1);
    f32x4 a1 = qk(fB);
    __builtin_amdgcn_s_setprio(0);
    if (s + 3 < 16) ldK(s + 3, fB);
    stP(a1, s + 1);
  }
  __syncthreads();

  // dump logits LDS -> global upper-half slots (4 full 2KB rows / instr)
  const int drow = tid >> 7;            // 0..3
  const int dcb  = (tid & 127) * 16;    // 0..2047
#pragma unroll
  for (int it = 0; it < 8; ++it) {
    int row = it * 4 + drow;
    half8 v = *(const half8*)(s_ + pswz(row, dcb));
    *(half8*)(Sl + (size_t)row * 4096 + 2048 + dcb) = v;
  }
}

// ---- k1b: PURE STREAM: logits + mask -> exp -> e + 1/rowsum ----
__global__ __launch_bounds__(256)
void k1b_exp(const float* __restrict__ mg, float* __restrict__ out,
             float* __restrict__ inv_ws) {
  char* Sb = (char*)(out + (size_t)kB * kTq * kDv);
  const int lane = threadIdx.x & 63;
  const size_t gw = (size_t)blockIdx.x * 4 + (threadIdx.x >> 6);
  const size_t rbase = gw * 8;   // 8 rows per wave

  for (int rr = 0; rr < 8; rr += 2) {
    const size_t r0 = rbase + rr, r1 = r0 + 1;
    char* s0 = Sb + r0 * 4096;
    char* s1 = Sb + r1 * 4096;
    // ---- all loads first ----
    half8 l0a = *(const half8*)(s0 + 2048 + lane * 32);
    half8 l0b = *(const half8*)(s0 + 2048 + lane * 32 + 16);
    half8 l1a = *(const half8*)(s1 + 2048 + lane * 32);
    half8 l1b = *(const half8*)(s1 + 2048 + lane * 32 + 16);
    f32x4 m0[4], m1[4];
#pragma unroll
    for (int c = 0; c < 4; ++c)
      m0[c] = *(const f32x4*)(mg + r0 * kTk + lane * 16 + c * 4);
#pragma unroll
    for (int c = 0; c < 4; ++c)
      m1[c] = *(const f32x4*)(mg + r1 * kTk + lane * 16 + c * 4);
    // ---- compute ----
    float e0[16], e1[16];
#pragma unroll
    for (int i = 0; i < 8; ++i) {
      e0[i]     = __expf((float)l0a[i] - 100.f * m0[i >> 2][i & 3]);
      e0[8 + i] = __expf((float)l0b[i] - 100.f * m0[2 + (i >> 2)][i & 3]);
      e1[i]     = __expf((float)l1a[i] - 100.f * m1[i >> 2][i & 3]);
      e1[8 + i] = __expf((float)l1b[i] - 100.f * m1[2 + (i >> 2)][i & 3]);
    }
    half8 v0a, v0b, v1a, v1b;
#pragma unroll
    for (int i = 0; i < 8; ++i) {
      v0a[i] = e0[i]; v0b[i] = e0[8 + i];
      v1a[i] = e1[i]; v1b[i] = e1[8 + i];
    }
    // ---- stores (lower 2KB: e) ----
    *(half8*)(s0 + lane * 32)      = v0a;
    *(half8*)(s0 + lane * 32 + 16) = v0b;
    *(half8*)(s1 + lane * 32)      = v1a;
    *(half8*)(s1 + lane * 32 + 16) = v1b;
    // ---- rowsums ----
    float rs0 = 0.f, rs1 = 0.f;
#pragma unroll
    for (int i = 0; i < 16; ++i) { rs0 += e0[i]; rs1 += e1[i]; }
    rs0 += __shfl_xor(rs0, 1);  rs0 += __shfl_xor(rs0, 2);
    rs0 += __shfl_xor(rs0, 4);  rs0 += __shfl_xor(rs0, 8);
    rs0 += __shfl_xor(rs0, 16); rs0 += __shfl_xor(rs0, 32);
    rs1 += __shfl_xor(rs1, 1);  rs1 += __shfl_xor(rs1, 2);
    rs1 += __shfl_xor(rs1, 4);  rs1 += __shfl_xor(rs1, 8);
    rs1 += __shfl_xor(rs1, 16); rs1 += __shfl_xor(rs1, 32);
    if (lane == 0) { inv_ws[r0] = 1.0f / rs0; inv_ws[r1] = 1.0f / rs1; }
  }
}

// ---- k2b: PV MFMA (e frags + VT) + ctx ----
__global__ __launch_bounds__(512, 4)
void k2b_pv(const _Float16* __restrict__ VT, const float* __restrict__ inv_ws,
            float* __restrict__ out) {
  __shared__ __align__(16) unsigned char s_[32768];

  const int tid  = threadIdx.x;
  const int lane = tid & 63;
  const int wid  = tid >> 6;     // 0..7
  const int l15  = lane & 15;
  const int lg   = lane >> 4;    // 0..3

  const int bi    = blockIdx.x;
  const int batch = (bi & 7) * 4 + (bi >> 9);
  const int q0    = ((bi >> 3) & 63) * 32;

  float* CTX = out + ((size_t)batch * kTq + q0) * kDv;
  const char* Eb = (const char*)(out + (size_t)kB * kTq * kDv) +
                   ((size_t)batch * kTq + q0) * 4096;
  const _Float16* Vb = VT + (size_t)batch * kDv * kTk;
  const float* INV = inv_ws + (size_t)batch * kTq + q0;

  const int wr = wid >> 2;
  const int wc = wid & 3;
  auto ldA = [&](int kc) -> half8 {
    return *(const half8*)(Eb + (size_t)(wr * 16 + l15) * 4096 +
                           kc * 64 + lg * 16);
  };
  auto ldV = [&](int kc) -> Frag4 {
    const _Float16* p = Vb + (size_t)(wc * 64 + l15) * kTk + kc * 32 + lg * 8;
    Frag4 f;
    f.a = *(const half8*)(p);
    f.b = *(const half8*)(p + (size_t)16 * kTk);
    f.c = *(const half8*)(p + (size_t)32 * kTk);
    f.d = *(const half8*)(p + (size_t)48 * kTk);
    return f;
  };
  f32x4 c0 = {0,0,0,0}, c1 = {0,0,0,0}, c2 = {0,0,0,0}, c3 = {0,0,0,0};
  auto mm = [&](const half8& p, const Frag4& v) {
    __builtin_amdgcn_s_setprio(1);
    c0 = __builtin_amdgcn_mfma_f32_16x16x32_f16(p, v.a, c0, 0, 0, 0);
    c1 = __builtin_amdgcn_mfma_f32_16x16x32_f16(p, v.b, c1, 0, 0, 0);
    c2 = __builtin_amdgcn_mfma_f32_16x16x32_f16(p, v.c, c2, 0, 0, 0);
    c3 = __builtin_amdgcn_mfma_f32_16x16x32_f16(p, v.d, c3, 0, 0, 0);
    __builtin_amdgcn_s_setprio(0);
  };
  half8 p0 = ldA(0), p1 = ldA(1), p2 = ldA(2), p3 = ldA(3);
  Frag4 v0 = ldV(0), v1 = ldV(1), v2 = ldV(2), v3 = ldV(3);
  for (int kc = 0; kc < 32; kc += 4) {
    mm(p0, v0); if (kc + 4 < 32) { p0 = ldA(kc + 4); v0 = ldV(kc + 4); }
    mm(p1, v1); if (kc + 5 < 32) { p1 = ldA(kc + 5); v1 = ldV(kc + 5); }
    mm(p2, v2); if (kc + 6 < 32) { p2 = ldA(kc + 6); v2 = ldV(kc + 6); }
    mm(p3, v3); if (kc + 7 < 32) { p3 = ldA(kc + 7); v3 = ldV(kc + 7); }
  }

  // ctx: stage to LDS, contiguous 1KB/row sweeps
  float* sf = (float*)s_;    // [32][256] f32
#pragma unroll
  for (int j = 0; j < 4; ++j) {
    const int row = wr * 16 + lg * 4 + j;
    sf[row * 256 + wc * 64 + l15]      = c0[j];
    sf[row * 256 + wc * 64 + 16 + l15] = c1[j];
    sf[row * 256 + wc * 64 + 32 + l15] = c2[j];
    sf[row * 256 + wc * 64 + 48 + l15] = c3[j];
  }
  __syncthreads();
  const int r0 = wid * 4;
#pragma unroll
  for (int rr = 0; rr < 4; ++rr) {
    const int r = r0 + rr;
    f32x4 v = *(const f32x4*)(sf + r * 256 + lane * 4);
    const float inv = INV[r];
    v[0] *= inv; v[1] *= inv; v[2] *= inv; v[3] *= inv;
    *(f32x4*)(CTX + (size_t)r * kDv + lane * 4) = v;
  }
}

// ---- k2a: PURE STREAM: e -> normalized score (full 4KB/row) ----
// Wave owns whole rows; upper chunk first; loads precede stores (dataflow).
__global__ __launch_bounds__(256)
void k2a_score(const float* __restrict__ inv_ws, float* __restrict__ out) {
  char* Sb = (char*)(out + (size_t)kB * kTq * kDv);
  const int lane = threadIdx.x & 63;
  const size_t gw = (size_t)blockIdx.x * 4 + (threadIdx.x >> 6);
  const size_t rbase = gw * 8;

  for (int rr = 0; rr < 8; rr += 2) {
    const size_t r0 = rbase + rr, r1 = r0 + 1;
    char* s0 = Sb + r0 * 4096;
    char* s1 = Sb + r1 * 4096;
    const float i0 = inv_ws[r0], i1 = inv_ws[r1];
    // ---- all 4 e-loads first ----
    half8 a1 = *(const half8*)(s0 + 1024 + lane * 16);   // row0 cols 512..1023
    half8 b1 = *(const half8*)(s1 + 1024 + lane * 16);
    half8 a0 = *(const half8*)(s0 + lane * 16);          // row0 cols 0..511
    half8 b0 = *(const half8*)(s1 + lane * 16);
    // ---- stores: upper chunks (clobber dead logits), then lower ----
    f32x4 o;
    o[0] = (float)a1[0] * i0; o[1] = (float)a1[1] * i0;
    o[2] = (float)a1[2] * i0; o[3] = (float)a1[3] * i0;
    *(f32x4*)(s0 + 2048 + lane * 32) = o;
    o[0] = (float)a1[4] * i0; o[1] = (float)a1[5] * i0;
    o[2] = (float)a1[6] * i0; o[3] = (float)a1[7] * i0;
    *(f32x4*)(s0 + 2048 + lane * 32 + 16) = o;
    o[0] = (float)b1[0] * i1; o[1] = (float)b1[1] * i1;
    o[2] = (float)b1[2] * i1; o[3] = (float)b1[3] * i1;
    *(f32x4*)(s1 + 2048 + lane * 32) = o;
    o[0] = (float)b1[4] * i1; o[1] = (float)b1[5] * i1;
    o[2] = (float)b1[6] * i1; o[3] = (float)b1[7] * i1;
    *(f32x4*)(s1 + 2048 + lane * 32 + 16) = o;
    // lower chunks: clobber e[0,2048) -- a1/b1 consumed, a0/b0 in regs
    o[0] = (float)a0[0] * i0; o[1] = (float)a0[1] * i0;
    o[2] = (float)a0[2] * i0; o[3] = (float)a0[3] * i0;
    *(f32x4*)(s0 + lane * 32) = o;
    o[0] = (float)a0[4] * i0; o[1] = (float)a0[5] * i0;
    o[2] = (float)a0[6] * i0; o[3] = (float)a0[7] * i0;
    *(f32x4*)(s0 + lane * 32 + 16) = o;
    o[0] = (float)b0[0] * i1; o[1] = (float)b0[1] * i1;
    o[2] = (float)b0[2] * i1; o[3] = (float)b0[3] * i1;
    *(f32x4*)(s1 + lane * 32) = o;
    o[0] = (float)b0[4] * i1; o[1] = (float)b0[5] * i1;
    o[2] = (float)b0[6] * i1; o[3] = (float)b0[7] * i1;
    *(f32x4*)(s1 + lane * 32 + 16) = o;
  }
}

}  // namespace

extern "C" void kernel_launch(void* const* d_in, const int* in_sizes, int n_in,
                              void* d_out, int out_size, void* d_ws, size_t ws_size,
                              hipStream_t stream) {
  const float* q = (const float*)d_in[0];
  const float* k = (const float*)d_in[1];
  const float* v = (const float*)d_in[2];
  const float* m = (const float*)d_in[3];
  float* out = (float*)d_out;
  (void)in_sizes; (void)n_in; (void)out_size; (void)ws_size;

  _Float16* k16 = (_Float16*)((char*)d_ws + kWsK);
  _Float16* vt  = (_Float16*)((char*)d_ws + kWsV);
  float*    inv = (float*)((char*)d_ws + kWsInv);

  hipLaunchKernelGGL(cvt_k, dim3(kB * kTk * kD / (256 * 8)), dim3(256), 0, stream,
                     k, k16);
  hipLaunchKernelGGL(trans_v, dim3(kB * 64), dim3(256), 0, stream, v, vt);
  hipLaunchKernelGGL(k1a_qkt, dim3(2048), dim3(512), 0, stream, q, k16, out);
  hipLaunchKernelGGL(k1b_exp, dim3(2048), dim3(256), 0, stream, m, out, inv);
  hipLaunchKernelGGL(k2b_pv, dim3(2048), dim3(512), 0, stream, vt, inv, out);
  hipLaunchKernelGGL(k2a_score, dim3(2048), dim3(256), 0, stream, inv, out);
}